// Round 7
// baseline (239.468 us; speedup 1.0000x reference)
//
#include <hip/hip_runtime.h>
#include <stdint.h>

#define G1  128   // blocks for hist/scatter passes
#define BSH 9     // log2(nodes per bucket)
#define BSZ 512   // nodes per bucket

typedef __attribute__((ext_vector_type(8))) short short8;
typedef __attribute__((ext_vector_type(4))) float f32x4;

// ---------------- threefry2x32 (JAX-compatible, 20 rounds) ----------------
#define TF_ROUND(x0, x1, r)                                                    \
  {                                                                            \
    x0 += x1;                                                                  \
    x1 = (x1 << r) | (x1 >> (32 - r));                                         \
    x1 ^= x0;                                                                  \
  }

__host__ __device__ inline void threefry2x32(uint32_t k0, uint32_t k1,
                                             uint32_t x0, uint32_t x1,
                                             uint32_t* o0, uint32_t* o1) {
  uint32_t ks2 = k0 ^ k1 ^ 0x1BD11BDAu;
  x0 += k0; x1 += k1;
  TF_ROUND(x0, x1, 13) TF_ROUND(x0, x1, 15) TF_ROUND(x0, x1, 26) TF_ROUND(x0, x1, 6)
  x0 += k1; x1 += ks2 + 1u;
  TF_ROUND(x0, x1, 17) TF_ROUND(x0, x1, 29) TF_ROUND(x0, x1, 16) TF_ROUND(x0, x1, 24)
  x0 += ks2; x1 += k0 + 2u;
  TF_ROUND(x0, x1, 13) TF_ROUND(x0, x1, 15) TF_ROUND(x0, x1, 26) TF_ROUND(x0, x1, 6)
  x0 += k0; x1 += k1 + 3u;
  TF_ROUND(x0, x1, 17) TF_ROUND(x0, x1, 29) TF_ROUND(x0, x1, 16) TF_ROUND(x0, x1, 24)
  x0 += k1; x1 += ks2 + 4u;
  TF_ROUND(x0, x1, 13) TF_ROUND(x0, x1, 15) TF_ROUND(x0, x1, 26) TF_ROUND(x0, x1, 6)
  x0 += ks2; x1 += k0 + 5u;
  *o0 = x0; *o1 = x1;
}

__device__ inline uint32_t tf_bits32(uint32_t k0, uint32_t k1, uint32_t ctr) {
  uint32_t a, b;
  threefry2x32(k0, k1, 0u, ctr, &a, &b);
  return a ^ b;
}

// bf16 helpers (RNE pack, bit-shift unpack)
__device__ inline uint32_t f2bf(float f) {
  uint32_t u = __float_as_uint(f);
  return (u + 0x7fffu + ((u >> 16) & 1u)) >> 16;
}
__device__ inline float bf_lo(uint32_t p) { return __uint_as_float(p << 16); }
__device__ inline float bf_hi(uint32_t p) { return __uint_as_float(p & 0xffff0000u); }

// ---------------- bucket counting-sort graph build ----------------
__global__ __launch_bounds__(256) void k_bhist(const int* __restrict__ dst,
                                               int* __restrict__ hist_t,
                                               int E, int NB, int chunk) {
  __shared__ int hist[256];
  for (int b = threadIdx.x; b < NB; b += 256) hist[b] = 0;
  __syncthreads();
  int e0 = blockIdx.x * chunk;
  int e1 = min(e0 + chunk, E);
  for (int e = e0 + threadIdx.x; e < e1; e += 256)
    atomicAdd(&hist[dst[e] >> BSH], 1);
  __syncthreads();
  for (int b = threadIdx.x; b < NB; b += 256)
    hist_t[b * G1 + blockIdx.x] = hist[b];
}

__global__ __launch_bounds__(256) void k_bscatter(const int* __restrict__ src,
                                                  const int* __restrict__ dst,
                                                  const int* __restrict__ scanned,
                                                  uint32_t* __restrict__ ebuf,
                                                  int E, int NB, int chunk) {
  __shared__ int cur[256];
  int g = blockIdx.x;
  for (int b = threadIdx.x; b < NB; b += 256) cur[b] = scanned[b * G1 + g];
  __syncthreads();
  int e0 = g * chunk, e1 = min(e0 + chunk, E);
  for (int e = e0 + threadIdx.x; e < e1; e += 256) {
    int d = dst[e];
    int slot = atomicAdd(&cur[d >> BSH], 1);
    ebuf[slot] = ((uint32_t)src[e] << BSH) | (uint32_t)(d & (BSZ - 1));
  }
}

__global__ __launch_bounds__(256) void k_bfinal(const uint32_t* __restrict__ ebuf,
                                                const int* __restrict__ scanned,
                                                int* __restrict__ rowptr,
                                                float* __restrict__ dis,
                                                int* __restrict__ csrc,
                                                int n, int NB, int E) {
  __shared__ int cnt[BSZ];
  __shared__ int sc[256];
  int b = blockIdx.x;
  int t = threadIdx.x;
  int seg0 = scanned[b * G1];
  int seg1 = scanned[(b + 1) * G1];
  for (int i = t; i < BSZ; i += 256) cnt[i] = 0;
  __syncthreads();
  for (int i = seg0 + t; i < seg1; i += 256)
    atomicAdd(&cnt[ebuf[i] & (BSZ - 1)], 1);
  __syncthreads();
  int a0 = cnt[2 * t], a1 = cnt[2 * t + 1];
  int s = a0 + a1;
  sc[t] = s;
  __syncthreads();
  for (int off = 1; off < 256; off <<= 1) {
    int tmp = (t >= off) ? sc[t - off] : 0;
    __syncthreads();
    sc[t] += tmp;
    __syncthreads();
  }
  int pre = sc[t] - s;
  int node0 = b * BSZ;
  int p0 = seg0 + pre;
  int p1 = p0 + a0;
  int nd0 = node0 + 2 * t, nd1 = nd0 + 1;
  if (nd0 <= n) rowptr[nd0] = p0;
  if (nd1 <= n) rowptr[nd1] = p1;
  if (nd0 < n) dis[nd0] = rsqrtf((float)(a0 + 1));
  if (nd1 < n) dis[nd1] = rsqrtf((float)(a1 + 1));
  cnt[2 * t] = p0;
  cnt[2 * t + 1] = p1;
  __syncthreads();
  for (int i = seg0 + t; i < seg1; i += 256) {
    uint32_t u = ebuf[i];
    int slot = atomicAdd(&cnt[u & (BSZ - 1)], 1);
    csrc[slot] = (int)(u >> BSH);
  }
  if (b == NB - 1 && t == 0) rowptr[n] = E;
}

// ---- merged: block 0 = exclusive scan of hist_t; blocks 1.. = GEMM1 ----
// GEMM1 (MFMA bf16): h1s[n,128] = bf16(x) @ bf16(W1), out *= dis-free (scaled later? no:
// scaling by dis happens here via dis[] computed by k_bfinal BEFORE this launch)
__global__ __launch_bounds__(256) void k_scan_gemm1(
    int* __restrict__ hist_t, int T,
    const float* __restrict__ x, const float* __restrict__ W,
    const float* __restrict__ dis, uint16_t* __restrict__ h, int n) {
  __shared__ uint16_t As[64][136];
  __shared__ uint16_t Bs[128][136];
  const int tid = threadIdx.x;
  if (blockIdx.x == 0) {
    // ---- 256-thread exclusive scan over hist_t[0..T), sentinel at [T] ----
    int* sh = (int*)&As[0][0];
    int per = (T + 255) >> 8;
    int b0 = min(tid * per, T);
    int b1 = min(b0 + per, T);
    int s = 0;
    for (int i = b0; i < b1; ++i) s += hist_t[i];
    sh[tid] = s;
    __syncthreads();
    for (int off = 1; off < 256; off <<= 1) {
      int t2 = (tid >= off) ? sh[tid - off] : 0;
      __syncthreads();
      sh[tid] += t2;
      __syncthreads();
    }
    int run = sh[tid] - s;  // exclusive prefix
    for (int i = b0; i < b1; ++i) { int v = hist_t[i]; hist_t[i] = run; run += v; }
    if (tid == 255) hist_t[T] = run;
    return;
  }
  const int rowBase = (blockIdx.x - 1) * 64;
  for (int i = tid; i < 64 * 32; i += 256) {
    int r = i >> 5, c4 = i & 31;
    float4 v = make_float4(0.f, 0.f, 0.f, 0.f);
    if (rowBase + r < n)
      v = ((const float4*)(x + (size_t)(rowBase + r) * 128))[c4];
    uint32_t lo = f2bf(v.x) | (f2bf(v.y) << 16);
    uint32_t hi = f2bf(v.z) | (f2bf(v.w) << 16);
    *(uint2*)&As[r][c4 * 4] = make_uint2(lo, hi);
  }
  {
    int k2 = tid >> 7;
    int c = tid & 127;
    for (int kk = 0; kk < 128; kk += 4) {
      int k = kk + k2 * 2;
      float w0 = W[k * 128 + c];
      float w1 = W[(k + 1) * 128 + c];
      *(uint32_t*)&Bs[c][k] = f2bf(w0) | (f2bf(w1) << 16);
    }
  }
  __syncthreads();
  const int wid = tid >> 6;
  const int lane = tid & 63;
  const int l15 = lane & 15;
  const int lhi = lane >> 4;
  f32x4 acc[8];
#pragma unroll
  for (int t = 0; t < 8; ++t) acc[t] = (f32x4){0.f, 0.f, 0.f, 0.f};
  const int arow = wid * 16 + l15;
#pragma unroll
  for (int ks = 0; ks < 4; ++ks) {
    short8 a = *(short8*)&As[arow][ks * 32 + lhi * 8];
#pragma unroll
    for (int ct = 0; ct < 8; ++ct) {
      short8 bfrag = *(short8*)&Bs[ct * 16 + l15][ks * 32 + lhi * 8];
      acc[ct] = __builtin_amdgcn_mfma_f32_16x16x32_bf16(a, bfrag, acc[ct], 0, 0, 0);
    }
  }
#pragma unroll
  for (int j = 0; j < 4; ++j) {
    int row = rowBase + wid * 16 + lhi * 4 + j;
    if (row < n) {
      float dv = dis[row];
#pragma unroll
      for (int ct = 0; ct < 8; ++ct)
        h[(size_t)row * 128 + ct * 16 + l15] = (uint16_t)f2bf(acc[ct][j] * dv);
    }
  }
}

// ---- gather layer 1: half-wave split, threefry hoisted to overlap edge loop ----
__global__ __launch_bounds__(256) void k_gather1(
    const int* __restrict__ rowptr, const int* __restrict__ csrc,
    const float* __restrict__ dis, const uint16_t* __restrict__ h1s,
    const float* __restrict__ bias, const float* __restrict__ pa,
    uint32_t* __restrict__ outbuf, int n, uint32_t k0, uint32_t k1) {
  int lane = threadIdx.x & 63;
  int v = (blockIdx.x * blockDim.x + threadIdx.x) >> 6;
  if (v >= n) return;
  // hoisted: dropout bits depend only on (v, lane) — overlap with edge loop
  uint32_t j0 = (uint32_t)v * 128u + (uint32_t)(lane * 2);
  uint32_t bits0 = tf_bits32(k0, k1, j0);
  uint32_t bits1 = tf_bits32(k0, k1, j0 + 1);
  const int half = lane >> 5;
  const int sl = lane & 31;
  const uint2* rowbase = (const uint2*)h1s;  // 8B units, 32 per row
  float a0 = 0.f, a1 = 0.f, a2 = 0.f, a3 = 0.f;
  if (half == 0) {
    uint2 r = rowbase[(size_t)v * 32 + sl];
    a0 = bf_lo(r.x); a1 = bf_hi(r.x); a2 = bf_lo(r.y); a3 = bf_hi(r.y);
  }
  int beg = rowptr[v];
  int deg = rowptr[v + 1] - beg;
  for (int base = 0; base < deg; base += 64) {
    int cnt = min(64, deg - base);
    int idx = base + lane;
    int sv = (idx < deg) ? csrc[beg + idx] : 0;
    int j = 0;
    for (; j + 4 <= cnt; j += 4) {
      int sA = __shfl(sv, j + half);
      int sB = __shfl(sv, j + 2 + half);
      uint2 rA = rowbase[(size_t)sA * 32 + sl];
      uint2 rB = rowbase[(size_t)sB * 32 + sl];
      a0 += bf_lo(rA.x); a1 += bf_hi(rA.x); a2 += bf_lo(rA.y); a3 += bf_hi(rA.y);
      a0 += bf_lo(rB.x); a1 += bf_hi(rB.x); a2 += bf_lo(rB.y); a3 += bf_hi(rB.y);
    }
    for (; j + 2 <= cnt; j += 2) {
      int s = __shfl(sv, j + half);
      uint2 r = rowbase[(size_t)s * 32 + sl];
      a0 += bf_lo(r.x); a1 += bf_hi(r.x); a2 += bf_lo(r.y); a3 += bf_hi(r.y);
    }
    if (j < cnt) {  // odd tail: half 0 only
      int s = __shfl(sv, cnt - 1);
      if (half == 0) {
        uint2 r = rowbase[(size_t)s * 32 + sl];
        a0 += bf_lo(r.x); a1 += bf_hi(r.x); a2 += bf_lo(r.y); a3 += bf_hi(r.y);
      }
    }
  }
  a0 += __shfl_xor(a0, 32);
  a1 += __shfl_xor(a1, 32);
  a2 += __shfl_xor(a2, 32);
  a3 += __shfl_xor(a3, 32);
  int srcl = lane >> 1;
  float b0 = __shfl(a0, srcl), b1 = __shfl(a1, srcl);
  float b2 = __shfl(a2, srcl), b3 = __shfl(a3, srcl);
  float v0 = (lane & 1) ? b2 : b0;
  float v1 = (lane & 1) ? b3 : b1;
  float dv = dis[v];
  float a = pa[0];
  int f0 = lane * 2;
  v0 = v0 * dv + bias[f0];
  v1 = v1 * dv + bias[f0 + 1];
  v0 = v0 >= 0.f ? v0 : a * v0;
  v1 = v1 >= 0.f ? v1 : a * v1;
  float r0 = (bits0 & 0x80000000u) ? 0.f : 2.f * v0;
  float r1 = (bits1 & 0x80000000u) ? 0.f : 2.f * v1;
  outbuf[(size_t)v * 64 + lane] = f2bf(r0) | (f2bf(r1) << 16);
}

// ---- GEMM2 (MFMA bf16): h2bf[n,16(bf16 packed x8)] = (hbf @ W2) * dis ----
__global__ __launch_bounds__(256) void k_gemm2(const uint32_t* __restrict__ hbf,
                                               const float* __restrict__ W2,
                                               const float* __restrict__ dis,
                                               uint32_t* __restrict__ h2bf, int n) {
  __shared__ uint16_t As[64][136];
  __shared__ uint16_t Bs[16][136];
  const int tid = threadIdx.x;
  const int rowBase = blockIdx.x * 64;
  for (int i = tid; i < 64 * 32; i += 256) {
    int r = i >> 5, c4 = i & 31;
    uint2 v = make_uint2(0u, 0u);
    if (rowBase + r < n)
      v = ((const uint2*)(hbf + (size_t)(rowBase + r) * 64))[c4];
    *(uint2*)&As[r][c4 * 4] = v;
  }
  {
    int c = tid & 15;
    int k8 = tid >> 4;  // 0..15
#pragma unroll
    for (int jj = 0; jj < 8; ++jj) {
      int k = k8 * 8 + jj;
      Bs[c][k] = (uint16_t)f2bf(W2[k * 16 + c]);
    }
  }
  __syncthreads();
  const int wid = tid >> 6;
  const int lane = tid & 63;
  const int l15 = lane & 15;
  const int lhi = lane >> 4;
  f32x4 acc = (f32x4){0.f, 0.f, 0.f, 0.f};
  const int arow = wid * 16 + l15;
#pragma unroll
  for (int ks = 0; ks < 4; ++ks) {
    short8 a = *(short8*)&As[arow][ks * 32 + lhi * 8];
    short8 bfrag = *(short8*)&Bs[l15][ks * 32 + lhi * 8];
    acc = __builtin_amdgcn_mfma_f32_16x16x32_bf16(a, bfrag, acc, 0, 0, 0);
  }
#pragma unroll
  for (int j = 0; j < 4; ++j) {
    int row = rowBase + wid * 16 + lhi * 4 + j;
    float val = (row < n) ? acc[j] * dis[row] : 0.f;
    float pv = __shfl_xor(val, 1);  // partner column (l15^1), same row
    if (row < n && (l15 & 1) == 0)
      h2bf[(size_t)row * 8 + (l15 >> 1)] = f2bf(val) | (f2bf(pv) << 16);
  }
}

// ---- gather layer 2 (bf16 rows, 8 lanes/node) + epilogue + fused GEMM3 ----
__global__ __launch_bounds__(256) void k_gather2(
    const int* __restrict__ rowptr, const int* __restrict__ csrc,
    const float* __restrict__ dis, const uint32_t* __restrict__ h2bf,
    const float* __restrict__ bias, const float* __restrict__ pa,
    const float* __restrict__ Wfc, const float* __restrict__ bfc,
    float* __restrict__ out, int n, uint32_t k0, uint32_t k1) {
  __shared__ float wfc[16][10];
  __shared__ float sbfc[10];
  __shared__ float sval[32][16];  // 32 nodes per block x 16 feats
  const int tid = threadIdx.x;
  if (tid < 160) wfc[tid >> 3][((tid & 7) + (tid >> 4)) % 10] =
      Wfc[(tid >> 3) * 10 + ((tid & 7) + (tid >> 4)) % 10];  // scrambled but complete? no — see below
  __syncthreads();
  // simple, correct staging (rewrite): first 160 threads load Wfc linearly
  if (tid < 160) ((float*)wfc)[tid] = Wfc[tid];
  if (tid < 10) sbfc[tid] = bfc[tid];
  __syncthreads();
  int gnode = (blockIdx.x * 256 + tid) >> 3;  // node
  int sub = tid & 7;                           // lane within node group
  int grp = tid >> 3;                          // node slot in block (0..31)
  if (gnode < n) {
    uint32_t selfp = h2bf[(size_t)gnode * 8 + sub];
    float acc0 = bf_lo(selfp);
    float acc1 = bf_hi(selfp);
    int beg = rowptr[gnode];
    int deg = rowptr[gnode + 1] - beg;
    for (int base = 0; base < deg; base += 8) {
      int cnt = min(8, deg - base);
      int idx = base + sub;
      int sv = (idx < deg) ? csrc[beg + idx] : 0;
      int j = 0;
      for (; j + 4 <= cnt; j += 4) {
        int s0 = __shfl(sv, j, 8), s1 = __shfl(sv, j + 1, 8);
        int s2 = __shfl(sv, j + 2, 8), s3 = __shfl(sv, j + 3, 8);
        uint32_t r0 = h2bf[(size_t)s0 * 8 + sub];
        uint32_t r1 = h2bf[(size_t)s1 * 8 + sub];
        uint32_t r2 = h2bf[(size_t)s2 * 8 + sub];
        uint32_t r3 = h2bf[(size_t)s3 * 8 + sub];
        acc0 += bf_lo(r0) + bf_lo(r1) + bf_lo(r2) + bf_lo(r3);
        acc1 += bf_hi(r0) + bf_hi(r1) + bf_hi(r2) + bf_hi(r3);
      }
      for (; j < cnt; ++j) {
        int s = __shfl(sv, j, 8);
        uint32_t r = h2bf[(size_t)s * 8 + sub];
        acc0 += bf_lo(r);
        acc1 += bf_hi(r);
      }
    }
    float dv = dis[gnode];
    float a = pa[0];
    int kf = sub * 2;
    float v0 = acc0 * dv + bias[kf];
    float v1 = acc1 * dv + bias[kf + 1];
    v0 = v0 >= 0.f ? v0 : a * v0;
    v1 = v1 >= 0.f ? v1 : a * v1;
    uint32_t c0 = (uint32_t)gnode * 16u + (uint32_t)kf;
    uint32_t bits0 = tf_bits32(k0, k1, c0);
    uint32_t bits1 = tf_bits32(k0, k1, c0 + 1);
    sval[grp][kf]     = (bits0 & 0x80000000u) ? 0.f : 2.f * v0;
    sval[grp][kf + 1] = (bits1 & 0x80000000u) ? 0.f : 2.f * v1;
  }
  __syncthreads();
  // fused GEMM3: lanes sub<5 compute 2 output columns each
  if (gnode < n && sub < 5) {
    int c = sub * 2;
    float o0 = sbfc[c], o1 = sbfc[c + 1];
#pragma unroll
    for (int k = 0; k < 16; ++k) {
      float hv = sval[grp][k];
      o0 += hv * wfc[k][c];
      o1 += hv * wfc[k][c + 1];
    }
    *(float2*)&out[(size_t)gnode * 10 + c] = make_float2(o0, o1);
  }
}

extern "C" void kernel_launch(void* const* d_in, const int* in_sizes, int n_in,
                              void* d_out, int out_size, void* d_ws, size_t ws_size,
                              hipStream_t stream) {
  const float* x   = (const float*)d_in[0];
  const int*   ei  = (const int*)d_in[1];
  const float* W1  = (const float*)d_in[2];
  const float* b1  = (const float*)d_in[3];
  const float* W2  = (const float*)d_in[4];
  const float* b2  = (const float*)d_in[5];
  const float* pa  = (const float*)d_in[6];
  const float* Wfc = (const float*)d_in[7];
  const float* bfc = (const float*)d_in[8];
  float* out = (float*)d_out;

  const int n = in_sizes[0] / 128;
  const int E = in_sizes[1] / 2;
  const int* src = ei;
  const int* dst = ei + E;

  const int NB = (n + BSZ - 1) / BSZ;
  const int T = NB * G1;
  const int chunk = (E + G1 - 1) / G1;

  char* w = (char*)d_ws;
  auto alloc = [&](size_t bytes) {
    char* p = w;
    w += (bytes + 255) & ~(size_t)255;
    return p;
  };
  float* dis      = (float*)alloc((size_t)n * 4);
  int* rowptr     = (int*)alloc((size_t)(n + 1) * 4);
  int* hist_t     = (int*)alloc((size_t)(T + 1) * 4);
  uint32_t* ebuf  = (uint32_t*)alloc((size_t)E * 4);
  int* csrc       = (int*)alloc((size_t)E * 4);
  uint16_t* h1bf  = (uint16_t*)alloc((size_t)n * 128 * 2);
  uint32_t* hbf   = (uint32_t*)alloc((size_t)n * 64 * 4);   // bf16 h (packed x2)
  uint32_t* h2bf  = (uint32_t*)alloc((size_t)n * 8 * 4);    // bf16 h2 (packed x2)

  uint32_t dk1_0, dk1_1, dk2_0, dk2_1;
  threefry2x32(0u, 42u, 0u, 0u, &dk1_0, &dk1_1);
  threefry2x32(0u, 42u, 0u, 1u, &dk2_0, &dk2_1);

  // 1. graph build: histogram; then {scan || gemm1} merged; scatter; finalize
  k_bhist<<<G1, 256, 0, stream>>>(dst, hist_t, E, NB, chunk);
  // NOTE: k_scan_gemm1 block 0 scans hist_t; blocks 1.. compute gemm1.
  // gemm1's dis-scaling must happen AFTER bfinal computes dis — but dis is
  // needed only in gemm1's epilogue... bfinal runs after. So gemm1 here must
  // NOT scale by dis. Instead, gather1 multiplies each gathered row by
  // nothing... => keep dis-scaling in gemm1 REQUIRES dis ready. Reorder:
  // run scan+gemm1 WITHOUT dis (raw bf16 h1), and fold dis into gather1's
  // shfl-broadcast? That reintroduces per-edge weights. Simpler: bfinal only
  // needs ebuf+scanned; dis comes from bfinal. So order: bhist, bscatter needs
  // scan... chain: bhist -> scan -> bscatter -> bfinal(dis) -> gemm1(dis).
  // To still hide the scan, merge scan with BSCATTER is impossible (dep).
  // => launch scan+gemm1 with gemm1 writing UNSCALED h1, and have gather1
  // scale per-row via dis[s]? No. Final choice: gemm1 output unscaled;
  // gather1 loads dis[s] per edge again? No — instead bfinal is independent
  // of gemm1, so: bhist -> {scan||gemm1(unscaled)} -> bscatter -> bfinal ->
  // gather1 reads dis[s]*dis[v] per edge? That reverts R4's win.
  //
  // Resolution: scale h1 rows by dis inside a tiny epilogue FUSED INTO
  // k_bfinal? bfinal is per-bucket = 512 rows x 128 feats = 64K bf16 = too
  // much work there. Cleanest: move dis computation EARLIER — deg of node v
  // = (rowptr not needed): k_bhist already counts per-bucket, not per-node.
  // Add a cheap k_deg-style pass? We removed it for good reason.
  //
  // Pragmatic: compute dis in k_bscatter? No per-node info either.
  // KEEP IT SIMPLE: run scan||gemm1 with gemm1 writing h1 * <nothing>, then
  // bscatter, then bfinal (computes dis), then a tiny k_scale kernel? Extra
  // 51MB traffic — bad. Instead: gather1 uses dis[v]*dis[s] weights again?
  // -- Decision: revert to R4-style: gemm1 scaled output requires dis first.
  // bfinal needs scan+scatter. So the scan CANNOT hide under gemm1 without
  // unscaled h1. Therefore hide scan under bscatter-prep instead: launch
  // order bhist -> scan (tiny, solo) -> {bscatter} -> {bfinal || gemm1-part}?
  // bfinal and gemm1 are independent ONLY if gemm1 doesn't need dis. It does.
  // => accept solo scan (it's ~3-5us). Launch plain order below.
  k_scan_gemm1<<<1, 256, 0, stream>>>(hist_t, T, x, W1, dis, h1bf, 0 /*scan only*/);
  k_bscatter<<<G1, 256, 0, stream>>>(src, dst, hist_t, ebuf, E, NB, chunk);
  k_bfinal<<<NB, 256, 0, stream>>>(ebuf, hist_t, rowptr, dis, csrc, n, NB, E);

  // 2. h1s = (x @ W1) * dis[row]  (MFMA bf16; blocks 1..; block 0 no-op scan of T=0)
  k_scan_gemm1<<<1 + (n + 63) / 64, 256, 0, stream>>>(hist_t, 0, x, W1, dis, h1bf, n);

  // 3. layer-1 aggregate + epilogue -> hbf (bf16)
  k_gather1<<<(n * 64 + 255) / 256, 256, 0, stream>>>(rowptr, csrc, dis, h1bf,
                                                      b1, pa, hbf, n, dk1_0, dk1_1);

  // 4. h2bf = (h @ W2) * dis[row]  (MFMA bf16, packed bf16 out)
  k_gemm2<<<(n + 63) / 64, 256, 0, stream>>>(hbf, W2, dis, h2bf, n);

  // 5. layer-2 aggregate + epilogue + fused gemm3 -> out
  k_gather2<<<(n * 8 + 255) / 256, 256, 0, stream>>>(rowptr, csrc, dis, h2bf,
                                                     b2, pa, Wfc, bfc, out, n,
                                                     dk2_0, dk2_1);
}

// Round 9
// 217.524 us; speedup vs baseline: 1.1009x; 1.1009x over previous
//
#include <hip/hip_runtime.h>
#include <stdint.h>

#define G1  128   // blocks for hist/scatter passes
#define BSH 9     // log2(nodes per bucket)
#define BSZ 512   // nodes per bucket

typedef __attribute__((ext_vector_type(8))) _Float16 f16x8;
typedef __attribute__((ext_vector_type(2))) _Float16 f16x2;
typedef __attribute__((ext_vector_type(2))) __fp16 fp16x2r;  // cvt_pkrtz return type
typedef __attribute__((ext_vector_type(4))) float f32x4;

// ---------------- threefry2x32 (JAX-compatible, 20 rounds) ----------------
#define TF_ROUND(x0, x1, r)                                                    \
  {                                                                            \
    x0 += x1;                                                                  \
    x1 = (x1 << r) | (x1 >> (32 - r));                                         \
    x1 ^= x0;                                                                  \
  }

__host__ __device__ inline void threefry2x32(uint32_t k0, uint32_t k1,
                                             uint32_t x0, uint32_t x1,
                                             uint32_t* o0, uint32_t* o1) {
  uint32_t ks2 = k0 ^ k1 ^ 0x1BD11BDAu;
  x0 += k0; x1 += k1;
  TF_ROUND(x0, x1, 13) TF_ROUND(x0, x1, 15) TF_ROUND(x0, x1, 26) TF_ROUND(x0, x1, 6)
  x0 += k1; x1 += ks2 + 1u;
  TF_ROUND(x0, x1, 17) TF_ROUND(x0, x1, 29) TF_ROUND(x0, x1, 16) TF_ROUND(x0, x1, 24)
  x0 += ks2; x1 += k0 + 2u;
  TF_ROUND(x0, x1, 13) TF_ROUND(x0, x1, 15) TF_ROUND(x0, x1, 26) TF_ROUND(x0, x1, 6)
  x0 += k0; x1 += k1 + 3u;
  TF_ROUND(x0, x1, 17) TF_ROUND(x0, x1, 29) TF_ROUND(x0, x1, 16) TF_ROUND(x0, x1, 24)
  x0 += k1; x1 += ks2 + 4u;
  TF_ROUND(x0, x1, 13) TF_ROUND(x0, x1, 15) TF_ROUND(x0, x1, 26) TF_ROUND(x0, x1, 6)
  x0 += ks2; x1 += k0 + 5u;
  *o0 = x0; *o1 = x1;
}

__device__ inline uint32_t tf_bits32(uint32_t k0, uint32_t k1, uint32_t ctr) {
  uint32_t a, b;
  threefry2x32(k0, k1, 0u, ctr, &a, &b);
  return a ^ b;
}

// fp16 helpers
__device__ inline float h2f_lo(uint32_t u) {
  union { uint32_t u; f16x2 h; } c; c.u = u;
  return (float)c.h.x;
}
__device__ inline float h2f_hi(uint32_t u) {
  union { uint32_t u; f16x2 h; } c; c.u = u;
  return (float)c.h.y;
}
__device__ inline uint32_t pk2h(float a, float b) {
  union { fp16x2r h; uint32_t u; } c;
  c.h = __builtin_amdgcn_cvt_pkrtz(a, b);
  return c.u;
}
__device__ inline uint16_t f2h(float a) {
  union { fp16x2r h; uint32_t u; } c;
  c.h = __builtin_amdgcn_cvt_pkrtz(a, 0.f);
  return (uint16_t)c.u;
}

// ---- merged launch: blocks 0..G1-1 = dst-bucket histogram; rest = GEMM1 ----
// GEMM1 (MFMA f16): h1[n,128] = f16(x) @ f16(W1)  (UNSCALED -> independent of build)
__global__ __launch_bounds__(256) void k_build1(
    const int* __restrict__ dst, int* __restrict__ hist_t, int E, int NB, int chunk,
    const float* __restrict__ x, const float* __restrict__ W,
    uint16_t* __restrict__ h, int n) {
  __shared__ char smem[(64 * 136 + 128 * 136) * 2];
  const int tid = threadIdx.x;
  if (blockIdx.x < G1) {
    int* hist = (int*)smem;
    for (int b = tid; b < NB; b += 256) hist[b] = 0;
    __syncthreads();
    int e0 = blockIdx.x * chunk;
    int e1 = min(e0 + chunk, E);
    for (int e = e0 + tid; e < e1; e += 256)
      atomicAdd(&hist[dst[e] >> BSH], 1);
    __syncthreads();
    for (int b = tid; b < NB; b += 256)
      hist_t[b * G1 + blockIdx.x] = hist[b];
    return;
  }
  // ---- GEMM1 part ----
  uint16_t (*As)[136] = (uint16_t(*)[136])smem;
  uint16_t (*Bs)[136] = (uint16_t(*)[136])(smem + 64 * 136 * 2);
  const int rowBase = (blockIdx.x - G1) * 64;
  for (int i = tid; i < 64 * 32; i += 256) {
    int r = i >> 5, c4 = i & 31;
    float4 v = make_float4(0.f, 0.f, 0.f, 0.f);
    if (rowBase + r < n)
      v = ((const float4*)(x + (size_t)(rowBase + r) * 128))[c4];
    *(uint2*)&As[r][c4 * 4] = make_uint2(pk2h(v.x, v.y), pk2h(v.z, v.w));
  }
  {
    int k2 = tid >> 7;
    int c = tid & 127;
    for (int kk = 0; kk < 128; kk += 4) {
      int k = kk + k2 * 2;
      *(uint32_t*)&Bs[c][k] = pk2h(W[k * 128 + c], W[(k + 1) * 128 + c]);
    }
  }
  __syncthreads();
  const int wid = tid >> 6;
  const int lane = tid & 63;
  const int l15 = lane & 15;
  const int lhi = lane >> 4;
  f32x4 acc[8];
#pragma unroll
  for (int t = 0; t < 8; ++t) acc[t] = (f32x4){0.f, 0.f, 0.f, 0.f};
  const int arow = wid * 16 + l15;
#pragma unroll
  for (int ks = 0; ks < 4; ++ks) {
    f16x8 a = *(f16x8*)&As[arow][ks * 32 + lhi * 8];
#pragma unroll
    for (int ct = 0; ct < 8; ++ct) {
      f16x8 bfrag = *(f16x8*)&Bs[ct * 16 + l15][ks * 32 + lhi * 8];
      acc[ct] = __builtin_amdgcn_mfma_f32_16x16x32_f16(a, bfrag, acc[ct], 0, 0, 0);
    }
  }
#pragma unroll
  for (int j = 0; j < 4; ++j) {
    int row = rowBase + wid * 16 + lhi * 4 + j;
    if (row < n) {
#pragma unroll
      for (int ct = 0; ct < 8; ++ct)
        h[(size_t)row * 128 + ct * 16 + l15] = f2h(acc[ct][j]);
    }
  }
}

// ---- exclusive scan over hist_t[0..T), sentinel at [T] ----
__global__ __launch_bounds__(1024) void k_bscan(int* __restrict__ h, int T) {
  __shared__ int sh[1024];
  int per = (T + 1023) >> 10;
  int b0 = min((int)threadIdx.x * per, T);
  int b1 = min(b0 + per, T);
  int s = 0;
  for (int i = b0; i < b1; ++i) s += h[i];
  sh[threadIdx.x] = s;
  __syncthreads();
  for (int off = 1; off < 1024; off <<= 1) {
    int t = (threadIdx.x >= off) ? sh[threadIdx.x - off] : 0;
    __syncthreads();
    sh[threadIdx.x] += t;
    __syncthreads();
  }
  int run = sh[threadIdx.x] - s;
  for (int i = b0; i < b1; ++i) { int v = h[i]; h[i] = run; run += v; }
  if (threadIdx.x == 1023) h[T] = run;
}

__global__ __launch_bounds__(256) void k_bscatter(const int* __restrict__ src,
                                                  const int* __restrict__ dst,
                                                  const int* __restrict__ scanned,
                                                  uint32_t* __restrict__ ebuf,
                                                  int E, int NB, int chunk) {
  __shared__ int cur[256];
  int g = blockIdx.x;
  for (int b = threadIdx.x; b < NB; b += 256) cur[b] = scanned[b * G1 + g];
  __syncthreads();
  int e0 = g * chunk, e1 = min(e0 + chunk, E);
  for (int e = e0 + threadIdx.x; e < e1; e += 256) {
    int d = dst[e];
    int slot = atomicAdd(&cur[d >> BSH], 1);
    ebuf[slot] = ((uint32_t)src[e] << BSH) | (uint32_t)(d & (BSZ - 1));
  }
}

__global__ __launch_bounds__(256) void k_bfinal(const uint32_t* __restrict__ ebuf,
                                                const int* __restrict__ scanned,
                                                int* __restrict__ rowptr,
                                                float* __restrict__ dis,
                                                int* __restrict__ csrc,
                                                int n, int NB, int E) {
  __shared__ int cnt[BSZ];
  __shared__ int sc[256];
  int b = blockIdx.x;
  int t = threadIdx.x;
  int seg0 = scanned[b * G1];
  int seg1 = scanned[(b + 1) * G1];
  for (int i = t; i < BSZ; i += 256) cnt[i] = 0;
  __syncthreads();
  for (int i = seg0 + t; i < seg1; i += 256)
    atomicAdd(&cnt[ebuf[i] & (BSZ - 1)], 1);
  __syncthreads();
  int a0 = cnt[2 * t], a1 = cnt[2 * t + 1];
  int s = a0 + a1;
  sc[t] = s;
  __syncthreads();
  for (int off = 1; off < 256; off <<= 1) {
    int tmp = (t >= off) ? sc[t - off] : 0;
    __syncthreads();
    sc[t] += tmp;
    __syncthreads();
  }
  int pre = sc[t] - s;
  int node0 = b * BSZ;
  int p0 = seg0 + pre;
  int p1 = p0 + a0;
  int nd0 = node0 + 2 * t, nd1 = nd0 + 1;
  if (nd0 <= n) rowptr[nd0] = p0;
  if (nd1 <= n) rowptr[nd1] = p1;
  if (nd0 < n) dis[nd0] = rsqrtf((float)(a0 + 1));
  if (nd1 < n) dis[nd1] = rsqrtf((float)(a1 + 1));
  cnt[2 * t] = p0;
  cnt[2 * t + 1] = p1;
  __syncthreads();
  for (int i = seg0 + t; i < seg1; i += 256) {
    uint32_t u = ebuf[i];
    int slot = atomicAdd(&cnt[u & (BSZ - 1)], 1);
    csrc[slot] = (int)(u >> BSH);
  }
  if (b == NB - 1 && t == 0) rowptr[n] = E;
}

// ---- gather layer 1: half-wave split, weighted fma, fp16 rows ----
// acc = dv*h1[v] + sum_s dis[s]*h1[s]; result * dv = GCN aggregate.
__global__ __launch_bounds__(256) void k_gather1(
    const int* __restrict__ rowptr, const int* __restrict__ csrc,
    const float* __restrict__ dis, const uint16_t* __restrict__ h1,
    const float* __restrict__ bias, const float* __restrict__ pa,
    uint32_t* __restrict__ outbuf, int n, uint32_t k0, uint32_t k1) {
  int lane = threadIdx.x & 63;
  int v = (blockIdx.x * blockDim.x + threadIdx.x) >> 6;
  if (v >= n) return;
  // hoisted dropout bits (depend only on (v,lane)) — overlap with edge loop
  uint32_t j0 = (uint32_t)v * 128u + (uint32_t)(lane * 2);
  uint32_t bits0 = tf_bits32(k0, k1, j0);
  uint32_t bits1 = tf_bits32(k0, k1, j0 + 1);
  const int half = lane >> 5;
  const int sl = lane & 31;
  const uint2* rowbase = (const uint2*)h1;  // 8B = 4 fp16, 32 per row
  float dv = dis[v];
  float a0 = 0.f, a1 = 0.f, a2 = 0.f, a3 = 0.f;
  if (half == 0) {
    uint2 r = rowbase[(size_t)v * 32 + sl];
    a0 = h2f_lo(r.x) * dv; a1 = h2f_hi(r.x) * dv;
    a2 = h2f_lo(r.y) * dv; a3 = h2f_hi(r.y) * dv;
  }
  int beg = rowptr[v];
  int deg = rowptr[v + 1] - beg;
  for (int base = 0; base < deg; base += 64) {
    int cnt = min(64, deg - base);
    int idx = base + lane;
    int sv = 0;
    float wd = 0.f;
    if (idx < deg) {
      sv = csrc[beg + idx];
      wd = dis[sv];
    }
    int j = 0;
    for (; j + 4 <= cnt; j += 4) {
      int sA = __shfl(sv, j + half);
      float wA = __shfl(wd, j + half);
      int sB = __shfl(sv, j + 2 + half);
      float wB = __shfl(wd, j + 2 + half);
      uint2 rA = rowbase[(size_t)sA * 32 + sl];
      uint2 rB = rowbase[(size_t)sB * 32 + sl];
      a0 = fmaf(h2f_lo(rA.x), wA, a0); a1 = fmaf(h2f_hi(rA.x), wA, a1);
      a2 = fmaf(h2f_lo(rA.y), wA, a2); a3 = fmaf(h2f_hi(rA.y), wA, a3);
      a0 = fmaf(h2f_lo(rB.x), wB, a0); a1 = fmaf(h2f_hi(rB.x), wB, a1);
      a2 = fmaf(h2f_lo(rB.y), wB, a2); a3 = fmaf(h2f_hi(rB.y), wB, a3);
    }
    for (; j + 2 <= cnt; j += 2) {
      int s = __shfl(sv, j + half);
      float w = __shfl(wd, j + half);
      uint2 r = rowbase[(size_t)s * 32 + sl];
      a0 = fmaf(h2f_lo(r.x), w, a0); a1 = fmaf(h2f_hi(r.x), w, a1);
      a2 = fmaf(h2f_lo(r.y), w, a2); a3 = fmaf(h2f_hi(r.y), w, a3);
    }
    if (j < cnt) {  // odd tail: half 0 only
      int s = __shfl(sv, cnt - 1);
      float w = __shfl(wd, cnt - 1);
      if (half == 0) {
        uint2 r = rowbase[(size_t)s * 32 + sl];
        a0 = fmaf(h2f_lo(r.x), w, a0); a1 = fmaf(h2f_hi(r.x), w, a1);
        a2 = fmaf(h2f_lo(r.y), w, a2); a3 = fmaf(h2f_hi(r.y), w, a3);
      }
    }
  }
  a0 += __shfl_xor(a0, 32);
  a1 += __shfl_xor(a1, 32);
  a2 += __shfl_xor(a2, 32);
  a3 += __shfl_xor(a3, 32);
  int srcl = lane >> 1;
  float b0 = __shfl(a0, srcl), b1 = __shfl(a1, srcl);
  float b2 = __shfl(a2, srcl), b3 = __shfl(a3, srcl);
  float v0 = (lane & 1) ? b2 : b0;
  float v1 = (lane & 1) ? b3 : b1;
  float a = pa[0];
  int f0 = lane * 2;
  v0 = v0 * dv + bias[f0];
  v1 = v1 * dv + bias[f0 + 1];
  v0 = v0 >= 0.f ? v0 : a * v0;
  v1 = v1 >= 0.f ? v1 : a * v1;
  float r0 = (bits0 & 0x80000000u) ? 0.f : 2.f * v0;
  float r1 = (bits1 & 0x80000000u) ? 0.f : 2.f * v1;
  outbuf[(size_t)v * 64 + lane] = pk2h(r0, r1);
}

// ---- GEMM2 (MFMA f16): h2[n,16] = hbf[n,128] @ f16(W2)  (unscaled, fp16 out) ----
__global__ __launch_bounds__(256) void k_gemm2(const uint32_t* __restrict__ hbf,
                                               const float* __restrict__ W2,
                                               uint32_t* __restrict__ h2, int n) {
  __shared__ uint16_t As[64][136];
  __shared__ uint16_t Bs[16][136];
  const int tid = threadIdx.x;
  const int rowBase = blockIdx.x * 64;
  for (int i = tid; i < 64 * 32; i += 256) {
    int r = i >> 5, c4 = i & 31;
    uint2 v = make_uint2(0u, 0u);
    if (rowBase + r < n)
      v = ((const uint2*)(hbf + (size_t)(rowBase + r) * 64))[c4];
    *(uint2*)&As[r][c4 * 4] = v;
  }
  {
    int c = tid & 15;
    int k8 = tid >> 4;  // 0..15
#pragma unroll
    for (int jj = 0; jj < 8; ++jj) {
      int k = k8 * 8 + jj;
      Bs[c][k] = f2h(W2[k * 16 + c]);
    }
  }
  __syncthreads();
  const int wid = tid >> 6;
  const int lane = tid & 63;
  const int l15 = lane & 15;
  const int lhi = lane >> 4;
  f32x4 acc = (f32x4){0.f, 0.f, 0.f, 0.f};
  const int arow = wid * 16 + l15;
#pragma unroll
  for (int ks = 0; ks < 4; ++ks) {
    f16x8 a = *(f16x8*)&As[arow][ks * 32 + lhi * 8];
    f16x8 bfrag = *(f16x8*)&Bs[l15][ks * 32 + lhi * 8];
    acc = __builtin_amdgcn_mfma_f32_16x16x32_f16(a, bfrag, acc, 0, 0, 0);
  }
#pragma unroll
  for (int j = 0; j < 4; ++j) {
    int row = rowBase + wid * 16 + lhi * 4 + j;
    float val = (row < n) ? acc[j] : 0.f;
    float pv = __shfl_xor(val, 1);  // partner column, same row
    if (row < n && (l15 & 1) == 0)
      h2[(size_t)row * 8 + (l15 >> 1)] = pk2h(val, pv);
  }
}

// ---- gather layer 2 (fp16 rows, 8 lanes/node, weighted) + fused GEMM3 ----
__global__ __launch_bounds__(256) void k_gather2(
    const int* __restrict__ rowptr, const int* __restrict__ csrc,
    const float* __restrict__ dis, const uint32_t* __restrict__ h2,
    const float* __restrict__ bias, const float* __restrict__ pa,
    const float* __restrict__ Wfc, const float* __restrict__ bfc,
    float* __restrict__ out, int n, uint32_t k0, uint32_t k1) {
  __shared__ float wfc[16][10];
  __shared__ float sbfc[10];
  __shared__ float sval[32][16];
  const int tid = threadIdx.x;
  if (tid < 160) ((float*)wfc)[tid] = Wfc[tid];
  if (tid < 10) sbfc[tid] = bfc[tid];
  __syncthreads();
  int gnode = (blockIdx.x * 256 + tid) >> 3;
  int sub = tid & 7;
  int grp = tid >> 3;
  if (gnode < n) {
    float dv = dis[gnode];
    uint32_t selfp = h2[(size_t)gnode * 8 + sub];
    float acc0 = h2f_lo(selfp) * dv;
    float acc1 = h2f_hi(selfp) * dv;
    int beg = rowptr[gnode];
    int deg = rowptr[gnode + 1] - beg;
    for (int base = 0; base < deg; base += 8) {
      int cnt = min(8, deg - base);
      int idx = base + sub;
      int sv = 0;
      float wd = 0.f;
      if (idx < deg) {
        sv = csrc[beg + idx];
        wd = dis[sv];
      }
      int j = 0;
      for (; j + 2 <= cnt; j += 2) {
        int s0 = __shfl(sv, j, 8), s1 = __shfl(sv, j + 1, 8);
        float w0 = __shfl(wd, j, 8), w1 = __shfl(wd, j + 1, 8);
        uint32_t r0 = h2[(size_t)s0 * 8 + sub];
        uint32_t r1 = h2[(size_t)s1 * 8 + sub];
        acc0 = fmaf(h2f_lo(r0), w0, acc0); acc1 = fmaf(h2f_hi(r0), w0, acc1);
        acc0 = fmaf(h2f_lo(r1), w1, acc0); acc1 = fmaf(h2f_hi(r1), w1, acc1);
      }
      for (; j < cnt; ++j) {
        int s = __shfl(sv, j, 8);
        float w = __shfl(wd, j, 8);
        uint32_t r = h2[(size_t)s * 8 + sub];
        acc0 = fmaf(h2f_lo(r), w, acc0);
        acc1 = fmaf(h2f_hi(r), w, acc1);
      }
    }
    float a = pa[0];
    int kf = sub * 2;
    float v0 = acc0 * dv + bias[kf];
    float v1 = acc1 * dv + bias[kf + 1];
    v0 = v0 >= 0.f ? v0 : a * v0;
    v1 = v1 >= 0.f ? v1 : a * v1;
    uint32_t c0 = (uint32_t)gnode * 16u + (uint32_t)kf;
    uint32_t bits0 = tf_bits32(k0, k1, c0);
    uint32_t bits1 = tf_bits32(k0, k1, c0 + 1);
    sval[grp][kf]     = (bits0 & 0x80000000u) ? 0.f : 2.f * v0;
    sval[grp][kf + 1] = (bits1 & 0x80000000u) ? 0.f : 2.f * v1;
  }
  __syncthreads();
  if (gnode < n && sub < 5) {
    int c = sub * 2;
    float o0 = sbfc[c], o1 = sbfc[c + 1];
#pragma unroll
    for (int k = 0; k < 16; ++k) {
      float hv = sval[grp][k];
      o0 += hv * wfc[k][c];
      o1 += hv * wfc[k][c + 1];
    }
    *(float2*)&out[(size_t)gnode * 10 + c] = make_float2(o0, o1);
  }
}

extern "C" void kernel_launch(void* const* d_in, const int* in_sizes, int n_in,
                              void* d_out, int out_size, void* d_ws, size_t ws_size,
                              hipStream_t stream) {
  const float* x   = (const float*)d_in[0];
  const int*   ei  = (const int*)d_in[1];
  const float* W1  = (const float*)d_in[2];
  const float* b1  = (const float*)d_in[3];
  const float* W2  = (const float*)d_in[4];
  const float* b2  = (const float*)d_in[5];
  const float* pa  = (const float*)d_in[6];
  const float* Wfc = (const float*)d_in[7];
  const float* bfc = (const float*)d_in[8];
  float* out = (float*)d_out;

  const int n = in_sizes[0] / 128;
  const int E = in_sizes[1] / 2;
  const int* src = ei;
  const int* dst = ei + E;

  const int NB = (n + BSZ - 1) / BSZ;
  const int T = NB * G1;
  const int chunk = (E + G1 - 1) / G1;

  char* w = (char*)d_ws;
  auto alloc = [&](size_t bytes) {
    char* p = w;
    w += (bytes + 255) & ~(size_t)255;
    return p;
  };
  float* dis      = (float*)alloc((size_t)n * 4);
  int* rowptr     = (int*)alloc((size_t)(n + 1) * 4);
  int* hist_t     = (int*)alloc((size_t)(T + 1) * 4);
  uint32_t* ebuf  = (uint32_t*)alloc((size_t)E * 4);
  int* csrc       = (int*)alloc((size_t)E * 4);
  uint16_t* h1f   = (uint16_t*)alloc((size_t)n * 128 * 2);  // fp16 h1 (unscaled)
  uint32_t* hbf   = (uint32_t*)alloc((size_t)n * 64 * 4);   // fp16 h (packed x2)
  uint32_t* h2f   = (uint32_t*)alloc((size_t)n * 8 * 4);    // fp16 h2 (packed x2)

  uint32_t dk1_0, dk1_1, dk2_0, dk2_1;
  threefry2x32(0u, 42u, 0u, 0u, &dk1_0, &dk1_1);
  threefry2x32(0u, 42u, 0u, 1u, &dk2_0, &dk2_1);

  // 1. {dst-bucket histogram || gemm1 (unscaled fp16)} in one launch
  k_build1<<<G1 + (n + 63) / 64, 256, 0, stream>>>(dst, hist_t, E, NB, chunk,
                                                   x, W1, h1f, n);
  // 2-4. scan -> scatter -> finalize (rowptr, dis, csrc)
  k_bscan<<<1, 1024, 0, stream>>>(hist_t, T);
  k_bscatter<<<G1, 256, 0, stream>>>(src, dst, hist_t, ebuf, E, NB, chunk);
  k_bfinal<<<NB, 256, 0, stream>>>(ebuf, hist_t, rowptr, dis, csrc, n, NB, E);

  // 5. layer-1 weighted aggregate + bias/prelu/dropout(dk1) -> hbf (fp16)
  k_gather1<<<(n * 64 + 255) / 256, 256, 0, stream>>>(rowptr, csrc, dis, h1f,
                                                      b1, pa, hbf, n, dk1_0, dk1_1);

  // 6. h2 = h @ W2 (MFMA f16, unscaled fp16 out)
  k_gemm2<<<(n + 63) / 64, 256, 0, stream>>>(hbf, W2, h2f, n);

  // 7. layer-2 weighted aggregate + epilogue + fused gemm3 -> out
  k_gather2<<<(n * 8 + 255) / 256, 256, 0, stream>>>(rowptr, csrc, dis, h2f,
                                                     b2, pa, Wfc, bfc, out, n,
                                                     dk2_0, dk2_1);
}